// Round 1
// baseline (965.115 us; speedup 1.0000x reference)
//
#include <hip/hip_runtime.h>
#include <math.h>

// GAT 3-layer: N=50000 nodes, E=800000 edges (+N self loops), HEADS=2, HID=64.
// Strategy: build dst-CSR once per call, then per layer:
//   gemm_att: h = X@W [N,128], a_src/a_dst per (node,head) via wave reduce
//   aggregate: one wave per dst node, online softmax over in-edges, coalesced
//              gather of h[src] (lane = channel), head-mean + bias + relu
// Pool: per-node dot with lin_w, atomic per-graph sum/count, finalize.

__device__ __forceinline__ float wave_sum(float v) {
  for (int off = 32; off; off >>= 1) v += __shfl_xor(v, off, 64);
  return v;
}

__global__ void init_kernel(int* __restrict__ deg, float* __restrict__ gsum,
                            int* __restrict__ gcnt, int n, int g) {
  int i = blockIdx.x * blockDim.x + threadIdx.x;
  if (i < n) deg[i] = 1;                 // self loop
  if (i < g) { gsum[i] = 0.f; gcnt[i] = 0; }
}

__global__ void count_kernel(const int* __restrict__ ei, int* __restrict__ deg, int e) {
  int i = blockIdx.x * blockDim.x + threadIdx.x;
  if (i < e) atomicAdd(&deg[ei[e + i]], 1);   // dst row of edge_index
}

// single-block exclusive scan (Hillis-Steele per 1024-chunk, serial carry)
__global__ void scan_kernel(const int* __restrict__ deg, int* __restrict__ row_ptr, int n) {
  __shared__ int sm[1024];
  __shared__ int carry;
  int tid = threadIdx.x;
  if (tid == 0) carry = 0;
  __syncthreads();
  for (int base = 0; base < n; base += 1024) {
    int i = base + tid;
    int v = (i < n) ? deg[i] : 0;
    sm[tid] = v;
    __syncthreads();
    for (int off = 1; off < 1024; off <<= 1) {
      int t = (tid >= off) ? sm[tid - off] : 0;
      __syncthreads();
      sm[tid] += t;
      __syncthreads();
    }
    int c = carry;
    if (i < n) row_ptr[i] = c + sm[tid] - v;   // exclusive
    int total = sm[1023];
    __syncthreads();
    if (tid == 0) carry = c + total;
    __syncthreads();
  }
  if (tid == 0) row_ptr[n] = carry;
}

__global__ void cursor_kernel(const int* __restrict__ row_ptr, int* __restrict__ cursor, int n) {
  int i = blockIdx.x * blockDim.x + threadIdx.x;
  if (i < n) cursor[i] = row_ptr[i];
}

__global__ void scatter_kernel(const int* __restrict__ ei, int* __restrict__ cursor,
                               int* __restrict__ csr_src, int n, int e) {
  int i = blockIdx.x * blockDim.x + threadIdx.x;
  if (i < n) {                               // self loop
    int p = atomicAdd(&cursor[i], 1);
    csr_src[p] = i;
  } else if (i < n + e) {
    int j = i - n;
    int s = ei[j];
    int d = ei[e + j];
    int p = atomicAdd(&cursor[d], 1);
    csr_src[p] = s;
  }
}

// block 256 = 4 waves: wave -> (row, head). wave0: row0/head0 cols 0..63,
// wave1: row0/head1 cols 64..127, waves 2,3: row1. att_src flat [2*64]=[128]
// matches col indexing directly.
template <int K>
__global__ void gemm_att(const float* __restrict__ X, const float* __restrict__ W,
                         const float* __restrict__ asw, const float* __restrict__ adw,
                         float* __restrict__ H, float* __restrict__ a_src,
                         float* __restrict__ a_dst, int N) {
  int row = blockIdx.x * 2 + (threadIdx.x >> 7);
  int col = threadIdx.x & 127;
  if (row >= N) return;
  const float* xr = X + (size_t)row * K;
  float acc = 0.f;
#pragma unroll
  for (int k = 0; k < K; k += 4) {
    float4 xv = *(const float4*)(xr + k);
    acc = fmaf(xv.x, W[(k + 0) * 128 + col], acc);
    acc = fmaf(xv.y, W[(k + 1) * 128 + col], acc);
    acc = fmaf(xv.z, W[(k + 2) * 128 + col], acc);
    acc = fmaf(xv.w, W[(k + 3) * 128 + col], acc);
  }
  H[(size_t)row * 128 + col] = acc;
  float vs = wave_sum(acc * asw[col]);
  float vd = wave_sum(acc * adw[col]);
  if ((threadIdx.x & 63) == 0) {
    int idx = row * 2 + (col >> 6);
    a_src[idx] = vs;
    a_dst[idx] = vd;
  }
}

// one wave per dst node; lane l = channel l of head0 AND head1.
__global__ void aggregate(const float* __restrict__ H, const float* __restrict__ a_src,
                          const float* __restrict__ a_dst, const float* __restrict__ bias,
                          const int* __restrict__ row_ptr, const int* __restrict__ csr_src,
                          float* __restrict__ out, int N) {
  int wid = blockIdx.x * (blockDim.x >> 6) + (threadIdx.x >> 6);
  if (wid >= N) return;
  int lane = threadIdx.x & 63;
  int beg = row_ptr[wid], end = row_ptr[wid + 1];
  float ad0 = a_dst[wid * 2], ad1 = a_dst[wid * 2 + 1];
  float m0 = -1e30f, s0 = 0.f, acc0 = 0.f;
  float m1 = -1e30f, s1 = 0.f, acc1 = 0.f;
  for (int j = beg; j < end; ++j) {
    int src = csr_src[j];
    float as0 = a_src[src * 2], as1 = a_src[src * 2 + 1];
    float e0 = as0 + ad0; e0 = (e0 > 0.f) ? e0 : 0.2f * e0;
    float e1 = as1 + ad1; e1 = (e1 > 0.f) ? e1 : 0.2f * e1;
    float nm0 = fmaxf(m0, e0), nm1 = fmaxf(m1, e1);
    float sc0 = __expf(m0 - nm0), sc1 = __expf(m1 - nm1);
    float p0 = __expf(e0 - nm0), p1 = __expf(e1 - nm1);
    const float* hs = H + (size_t)src * 128;
    float h0 = hs[lane];
    float h1 = hs[64 + lane];
    s0 = s0 * sc0 + p0;
    s1 = s1 * sc1 + p1;
    acc0 = acc0 * sc0 + h0 * p0;
    acc1 = acc1 * sc1 + h1 * p1;
    m0 = nm0; m1 = nm1;
  }
  float r0 = acc0 / fmaxf(s0, 1e-16f);
  float r1 = acc1 / fmaxf(s1, 1e-16f);
  float v = 0.5f * (r0 + r1) + bias[lane];
  out[(size_t)wid * 64 + lane] = (v > 0.f) ? v : 0.f;
}

// per-node dot with lin_w (linear commutes past the mean), atomic per-graph
__global__ void pool_kernel(const float* __restrict__ X, const float* __restrict__ lw,
                            const int* __restrict__ batch, float* __restrict__ gsum,
                            int* __restrict__ gcnt, int N) {
  int wid = blockIdx.x * (blockDim.x >> 6) + (threadIdx.x >> 6);
  if (wid >= N) return;
  int lane = threadIdx.x & 63;
  float v = X[(size_t)wid * 64 + lane] * lw[lane];
  v = wave_sum(v);
  if (lane == 0) {
    int g = batch[wid];
    atomicAdd(&gsum[g], v);
    atomicAdd(&gcnt[g], 1);
  }
}

__global__ void finalize_kernel(const float* __restrict__ gsum, const int* __restrict__ gcnt,
                                const float* __restrict__ lb, float* __restrict__ out, int G) {
  int g = blockIdx.x * blockDim.x + threadIdx.x;
  if (g < G) out[g] = gsum[g] / fmaxf((float)gcnt[g], 1.f) + lb[0];
}

extern "C" void kernel_launch(void* const* d_in, const int* in_sizes, int n_in,
                              void* d_out, int out_size, void* d_ws, size_t ws_size,
                              hipStream_t stream) {
  const float* x   = (const float*)d_in[0];
  const int* ei    = (const int*)d_in[1];
  const int* batch = (const int*)d_in[2];
  const float* W1  = (const float*)d_in[3];
  const float* as1 = (const float*)d_in[4];
  const float* ad1 = (const float*)d_in[5];
  const float* b1  = (const float*)d_in[6];
  const float* W2  = (const float*)d_in[7];
  const float* as2 = (const float*)d_in[8];
  const float* ad2 = (const float*)d_in[9];
  const float* b2  = (const float*)d_in[10];
  const float* W3  = (const float*)d_in[11];
  const float* as3 = (const float*)d_in[12];
  const float* ad3 = (const float*)d_in[13];
  const float* b3  = (const float*)d_in[14];
  const float* lw  = (const float*)d_in[15];
  const float* lb  = (const float*)d_in[16];
  float* out = (float*)d_out;

  const int N = in_sizes[0] / 128;   // 50000
  const int E = in_sizes[1] / 2;     // 800000
  const int ET = N + E;              // with self loops
  const int G = out_size;            // 2500

  char* p = (char*)d_ws;
  auto take = [&](size_t bytes) {
    char* r = p;
    p += (bytes + 255) & ~(size_t)255;
    return r;
  };
  int* deg      = (int*)take((size_t)N * 4);
  int* row_ptr  = (int*)take((size_t)(N + 1) * 4);
  int* cursor   = (int*)take((size_t)N * 4);
  int* csr      = (int*)take((size_t)ET * 4);
  float* H      = (float*)take((size_t)N * 128 * 4);
  float* a_src  = (float*)take((size_t)N * 2 * 4);
  float* a_dst  = (float*)take((size_t)N * 2 * 4);
  float* bufA   = (float*)take((size_t)N * 64 * 4);
  float* bufB   = (float*)take((size_t)N * 64 * 4);
  float* gsum   = (float*)take((size_t)G * 4);
  int* gcnt     = (int*)take((size_t)G * 4);
  (void)ws_size; (void)n_in;

  // ---- CSR build (dst-sorted, with self loops) ----
  init_kernel<<<(N + 255) / 256, 256, 0, stream>>>(deg, gsum, gcnt, N, G);
  count_kernel<<<(E + 255) / 256, 256, 0, stream>>>(ei, deg, E);
  scan_kernel<<<1, 1024, 0, stream>>>(deg, row_ptr, N);
  cursor_kernel<<<(N + 255) / 256, 256, 0, stream>>>(row_ptr, cursor, N);
  scatter_kernel<<<(ET + 255) / 256, 256, 0, stream>>>(ei, cursor, csr, N, E);

  // ---- layer 1 (K=128) ----
  gemm_att<128><<<(N + 1) / 2, 256, 0, stream>>>(x, W1, as1, ad1, H, a_src, a_dst, N);
  aggregate<<<(N + 3) / 4, 256, 0, stream>>>(H, a_src, a_dst, b1, row_ptr, csr, bufA, N);
  // ---- layer 2 (K=64) ----
  gemm_att<64><<<(N + 1) / 2, 256, 0, stream>>>(bufA, W2, as2, ad2, H, a_src, a_dst, N);
  aggregate<<<(N + 3) / 4, 256, 0, stream>>>(H, a_src, a_dst, b2, row_ptr, csr, bufB, N);
  // ---- layer 3 (K=64) ----
  gemm_att<64><<<(N + 1) / 2, 256, 0, stream>>>(bufB, W3, as3, ad3, H, a_src, a_dst, N);
  aggregate<<<(N + 3) / 4, 256, 0, stream>>>(H, a_src, a_dst, b3, row_ptr, csr, bufA, N);

  // ---- pool + linear ----
  pool_kernel<<<(N + 3) / 4, 256, 0, stream>>>(bufA, lw, batch, gsum, gcnt, N);
  finalize_kernel<<<(G + 255) / 256, 256, 0, stream>>>(gsum, gcnt, lb, out, G);
}

// Round 2
// 708.837 us; speedup vs baseline: 1.3615x; 1.3615x over previous
//
#include <hip/hip_runtime.h>
#include <math.h>

// GAT 3-layer: N=50000 nodes, E=800000 edges (+N self loops), HEADS=2, HID=64.
// R2: gemm rewritten with LDS X-tile + 8x4 register blocking (was 1 load/FMA,
// VALUBusy 18%). W stays in global (L1-resident, 32-64KB, shared by all blocks).
// a_src/a_dst split into a small wave-reduce kernel.

__device__ __forceinline__ float wave_sum(float v) {
  for (int off = 32; off; off >>= 1) v += __shfl_xor(v, off, 64);
  return v;
}

__global__ void init_kernel(int* __restrict__ deg, float* __restrict__ gsum,
                            int* __restrict__ gcnt, int n, int g) {
  int i = blockIdx.x * blockDim.x + threadIdx.x;
  if (i < n) deg[i] = 1;                 // self loop
  if (i < g) { gsum[i] = 0.f; gcnt[i] = 0; }
}

__global__ void count_kernel(const int* __restrict__ ei, int* __restrict__ deg, int e) {
  int i = blockIdx.x * blockDim.x + threadIdx.x;
  if (i < e) atomicAdd(&deg[ei[e + i]], 1);   // dst row of edge_index
}

// single-block exclusive scan (Hillis-Steele per 1024-chunk, serial carry)
__global__ void scan_kernel(const int* __restrict__ deg, int* __restrict__ row_ptr, int n) {
  __shared__ int sm[1024];
  __shared__ int carry;
  int tid = threadIdx.x;
  if (tid == 0) carry = 0;
  __syncthreads();
  for (int base = 0; base < n; base += 1024) {
    int i = base + tid;
    int v = (i < n) ? deg[i] : 0;
    sm[tid] = v;
    __syncthreads();
    for (int off = 1; off < 1024; off <<= 1) {
      int t = (tid >= off) ? sm[tid - off] : 0;
      __syncthreads();
      sm[tid] += t;
      __syncthreads();
    }
    int c = carry;
    if (i < n) row_ptr[i] = c + sm[tid] - v;   // exclusive
    int total = sm[1023];
    __syncthreads();
    if (tid == 0) carry = c + total;
    __syncthreads();
  }
  if (tid == 0) row_ptr[n] = carry;
}

__global__ void cursor_kernel(const int* __restrict__ row_ptr, int* __restrict__ cursor, int n) {
  int i = blockIdx.x * blockDim.x + threadIdx.x;
  if (i < n) cursor[i] = row_ptr[i];
}

__global__ void scatter_kernel(const int* __restrict__ ei, int* __restrict__ cursor,
                               int* __restrict__ csr_src, int n, int e) {
  int i = blockIdx.x * blockDim.x + threadIdx.x;
  if (i < n) {                               // self loop
    int p = atomicAdd(&cursor[i], 1);
    csr_src[p] = i;
  } else if (i < n + e) {
    int j = i - n;
    int s = ei[j];
    int d = ei[e + j];
    int p = atomicAdd(&cursor[d], 1);
    csr_src[p] = s;
  }
}

// Tiled gemm: 64-row x 128-col block, 256 threads.
// thread: cgrp = tid&31 -> cols [cgrp*4, +4); rg = tid>>5 -> rows [rg*8, +8).
// X tile in LDS (pad K+1: lanes sharing rg broadcast, 2 rgroups/wave hit
// different banks). W read from global float4 (L1-hot: every block reads the
// same 32-64KB). 32 acc/thread -> 32 FMA per (1 global b128 + 8 lds b32).
template <int K>
__global__ __launch_bounds__(256) void gemm_tiled(const float* __restrict__ X,
                                                  const float* __restrict__ W,
                                                  float* __restrict__ H, int N) {
  __shared__ float Xs[64 * (K + 1)];
  int tid = threadIdx.x;
  int row0 = blockIdx.x * 64;

  for (int idx = tid; idx < 64 * K; idx += 256) {
    int r = idx / K;
    int k = idx - r * K;
    int gr = row0 + r;
    if (gr >= N) gr = N - 1;          // clamp pad rows (stores are guarded)
    Xs[r * (K + 1) + k] = X[(size_t)gr * K + k];
  }
  __syncthreads();

  int cgrp = tid & 31;
  int c0 = cgrp * 4;
  int rg = tid >> 5;
  const float* wp = W + c0;
  float acc[8][4] = {};

#pragma unroll 4
  for (int k = 0; k < K; ++k) {
    float4 w4 = *(const float4*)(wp + k * 128);
#pragma unroll
    for (int j = 0; j < 8; ++j) {
      float xv = Xs[(rg * 8 + j) * (K + 1) + k];
      acc[j][0] = fmaf(xv, w4.x, acc[j][0]);
      acc[j][1] = fmaf(xv, w4.y, acc[j][1]);
      acc[j][2] = fmaf(xv, w4.z, acc[j][2]);
      acc[j][3] = fmaf(xv, w4.w, acc[j][3]);
    }
  }

#pragma unroll
  for (int j = 0; j < 8; ++j) {
    int r = row0 + rg * 8 + j;
    if (r < N) {
      float4 v = make_float4(acc[j][0], acc[j][1], acc[j][2], acc[j][3]);
      *(float4*)(H + (size_t)r * 128 + c0) = v;
    }
  }
}

// per (node,head) attention scalars via wave reduction over 64 channels
__global__ void att_kernel(const float* __restrict__ H, const float* __restrict__ asw,
                           const float* __restrict__ adw, float* __restrict__ a_src,
                           float* __restrict__ a_dst, int N) {
  int wid = blockIdx.x * (blockDim.x >> 6) + (threadIdx.x >> 6);
  if (wid >= N) return;
  int lane = threadIdx.x & 63;
  float h0 = H[(size_t)wid * 128 + lane];
  float h1 = H[(size_t)wid * 128 + 64 + lane];
  float s0 = wave_sum(h0 * asw[lane]);
  float d0 = wave_sum(h0 * adw[lane]);
  float s1 = wave_sum(h1 * asw[64 + lane]);
  float d1 = wave_sum(h1 * adw[64 + lane]);
  if (lane == 0) {
    a_src[wid * 2] = s0;
    a_dst[wid * 2] = d0;
    a_src[wid * 2 + 1] = s1;
    a_dst[wid * 2 + 1] = d1;
  }
}

// one wave per dst node; lane l = channel l of head0 AND head1.
__global__ void aggregate(const float* __restrict__ H, const float* __restrict__ a_src,
                          const float* __restrict__ a_dst, const float* __restrict__ bias,
                          const int* __restrict__ row_ptr, const int* __restrict__ csr_src,
                          float* __restrict__ out, int N) {
  int wid = blockIdx.x * (blockDim.x >> 6) + (threadIdx.x >> 6);
  if (wid >= N) return;
  int lane = threadIdx.x & 63;
  int beg = row_ptr[wid], end = row_ptr[wid + 1];
  float ad0 = a_dst[wid * 2], ad1 = a_dst[wid * 2 + 1];
  float m0 = -1e30f, s0 = 0.f, acc0 = 0.f;
  float m1 = -1e30f, s1 = 0.f, acc1 = 0.f;
  for (int j = beg; j < end; ++j) {
    int src = csr_src[j];
    float as0 = a_src[src * 2], as1 = a_src[src * 2 + 1];
    float e0 = as0 + ad0; e0 = (e0 > 0.f) ? e0 : 0.2f * e0;
    float e1 = as1 + ad1; e1 = (e1 > 0.f) ? e1 : 0.2f * e1;
    float nm0 = fmaxf(m0, e0), nm1 = fmaxf(m1, e1);
    float sc0 = __expf(m0 - nm0), sc1 = __expf(m1 - nm1);
    float p0 = __expf(e0 - nm0), p1 = __expf(e1 - nm1);
    const float* hs = H + (size_t)src * 128;
    float h0 = hs[lane];
    float h1 = hs[64 + lane];
    s0 = s0 * sc0 + p0;
    s1 = s1 * sc1 + p1;
    acc0 = acc0 * sc0 + h0 * p0;
    acc1 = acc1 * sc1 + h1 * p1;
    m0 = nm0; m1 = nm1;
  }
  float r0 = acc0 / fmaxf(s0, 1e-16f);
  float r1 = acc1 / fmaxf(s1, 1e-16f);
  float v = 0.5f * (r0 + r1) + bias[lane];
  out[(size_t)wid * 64 + lane] = (v > 0.f) ? v : 0.f;
}

// per-node dot with lin_w (linear commutes past the mean), atomic per-graph
__global__ void pool_kernel(const float* __restrict__ X, const float* __restrict__ lw,
                            const int* __restrict__ batch, float* __restrict__ gsum,
                            int* __restrict__ gcnt, int N) {
  int wid = blockIdx.x * (blockDim.x >> 6) + (threadIdx.x >> 6);
  if (wid >= N) return;
  int lane = threadIdx.x & 63;
  float v = X[(size_t)wid * 64 + lane] * lw[lane];
  v = wave_sum(v);
  if (lane == 0) {
    int g = batch[wid];
    atomicAdd(&gsum[g], v);
    atomicAdd(&gcnt[g], 1);
  }
}

__global__ void finalize_kernel(const float* __restrict__ gsum, const int* __restrict__ gcnt,
                                const float* __restrict__ lb, float* __restrict__ out, int G) {
  int g = blockIdx.x * blockDim.x + threadIdx.x;
  if (g < G) out[g] = gsum[g] / fmaxf((float)gcnt[g], 1.f) + lb[0];
}

extern "C" void kernel_launch(void* const* d_in, const int* in_sizes, int n_in,
                              void* d_out, int out_size, void* d_ws, size_t ws_size,
                              hipStream_t stream) {
  const float* x   = (const float*)d_in[0];
  const int* ei    = (const int*)d_in[1];
  const int* batch = (const int*)d_in[2];
  const float* W1  = (const float*)d_in[3];
  const float* as1 = (const float*)d_in[4];
  const float* ad1 = (const float*)d_in[5];
  const float* b1  = (const float*)d_in[6];
  const float* W2  = (const float*)d_in[7];
  const float* as2 = (const float*)d_in[8];
  const float* ad2 = (const float*)d_in[9];
  const float* b2  = (const float*)d_in[10];
  const float* W3  = (const float*)d_in[11];
  const float* as3 = (const float*)d_in[12];
  const float* ad3 = (const float*)d_in[13];
  const float* b3  = (const float*)d_in[14];
  const float* lw  = (const float*)d_in[15];
  const float* lb  = (const float*)d_in[16];
  float* out = (float*)d_out;

  const int N = in_sizes[0] / 128;   // 50000
  const int E = in_sizes[1] / 2;     // 800000
  const int ET = N + E;              // with self loops
  const int G = out_size;            // 2500

  char* p = (char*)d_ws;
  auto take = [&](size_t bytes) {
    char* r = p;
    p += (bytes + 255) & ~(size_t)255;
    return r;
  };
  int* deg      = (int*)take((size_t)N * 4);
  int* row_ptr  = (int*)take((size_t)(N + 1) * 4);
  int* cursor   = (int*)take((size_t)N * 4);
  int* csr      = (int*)take((size_t)ET * 4);
  float* H      = (float*)take((size_t)N * 128 * 4);
  float* a_src  = (float*)take((size_t)N * 2 * 4);
  float* a_dst  = (float*)take((size_t)N * 2 * 4);
  float* bufA   = (float*)take((size_t)N * 64 * 4);
  float* bufB   = (float*)take((size_t)N * 64 * 4);
  float* gsum   = (float*)take((size_t)G * 4);
  int* gcnt     = (int*)take((size_t)G * 4);
  (void)ws_size; (void)n_in;

  // ---- CSR build (dst-sorted, with self loops) ----
  init_kernel<<<(N + 255) / 256, 256, 0, stream>>>(deg, gsum, gcnt, N, G);
  count_kernel<<<(E + 255) / 256, 256, 0, stream>>>(ei, deg, E);
  scan_kernel<<<1, 1024, 0, stream>>>(deg, row_ptr, N);
  cursor_kernel<<<(N + 255) / 256, 256, 0, stream>>>(row_ptr, cursor, N);
  scatter_kernel<<<(ET + 255) / 256, 256, 0, stream>>>(ei, cursor, csr, N, E);

  const int gblk = (N + 63) / 64;
  const int wblk = (N + 3) / 4;

  // ---- layer 1 (K=128) ----
  gemm_tiled<128><<<gblk, 256, 0, stream>>>(x, W1, H, N);
  att_kernel<<<wblk, 256, 0, stream>>>(H, as1, ad1, a_src, a_dst, N);
  aggregate<<<wblk, 256, 0, stream>>>(H, a_src, a_dst, b1, row_ptr, csr, bufA, N);
  // ---- layer 2 (K=64) ----
  gemm_tiled<64><<<gblk, 256, 0, stream>>>(bufA, W2, H, N);
  att_kernel<<<wblk, 256, 0, stream>>>(H, as2, ad2, a_src, a_dst, N);
  aggregate<<<wblk, 256, 0, stream>>>(H, a_src, a_dst, b2, row_ptr, csr, bufB, N);
  // ---- layer 3 (K=64) ----
  gemm_tiled<64><<<gblk, 256, 0, stream>>>(bufB, W3, H, N);
  att_kernel<<<wblk, 256, 0, stream>>>(H, as3, ad3, a_src, a_dst, N);
  aggregate<<<wblk, 256, 0, stream>>>(H, a_src, a_dst, b3, row_ptr, csr, bufA, N);

  // ---- pool + linear ----
  pool_kernel<<<wblk, 256, 0, stream>>>(bufA, lw, batch, gsum, gcnt, N);
  finalize_kernel<<<(G + 255) / 256, 256, 0, stream>>>(gsum, gcnt, lb, out, G);
}